// Round 1
// baseline (334.702 us; speedup 1.0000x reference)
//
#include <hip/hip_runtime.h>

// FlowNetC correlation: B=8, C=256, H=W=64, 441 displacements (21x21, stride 2, max 20)
// out[b, r*21+ix, y, x] = (1/256) * sum_c in1[b,c,y,x] * in2[b,c, y+2r-20, x+2ix-20]
// (in2 zero-padded outside [0,64))
//
// Block = (b, y): 512 blocks of 512 threads. Per-thread register tile: 8 x  x  8 dx
// (dx padded 21->24). LDS stages Kc=4 channels of the in1 row and all 21 displaced
// in2 rows (104 cols + zero pad, stride 112). Sliding-window reuse: per channel a
// thread reads 8 in1 + 24 in2 floats (8 x float4, 16B-aligned) for 64 FMAs ->
// compute-bound (LDS issue ~96 cyc < VALU 128 cyc per channel per wave).

constexpr int KC   = 4;
constexpr int NROW = 21;    // dy rows
constexpr int NCOL = 112;   // padded LDS row stride (104 used)

__global__ __launch_bounds__(512, 4)
void corr_kernel(const float* __restrict__ in1,
                 const float* __restrict__ in2,
                 float* __restrict__ out)
{
    __shared__ float lds2[KC][NROW][NCOL];
    __shared__ float lds1[KC][64];

    const int tid = threadIdx.x;
    const int b = blockIdx.x & 7;    // b = blk%8 -> same-b blocks share an XCD L2
    const int y = blockIdx.x >> 3;

    const int xg   = tid & 7;          // 8 x-groups of 8
    const int dxg  = (tid >> 3) % 3;   // 3 dx-groups of 8 (covers 24 >= 21)
    const int r    = tid / 24;         // dy index; >=21 -> idle lane (8 of 512)
    const bool active = (r < 21);

    float acc[8][8];
#pragma unroll
    for (int j = 0; j < 8; ++j)
#pragma unroll
        for (int i = 0; i < 8; ++i) acc[j][i] = 0.f;

    const int in_b_off = b * (256 * 64 * 64);
    const int wbase = (xg << 3) + (dxg << 4);   // in2 LDS window base col (16B aligned)

    for (int c0 = 0; c0 < 256; c0 += KC) {
        // ---- stage in1 row chunk: KC*64 floats = 64 float4 slots ----
        if (tid < 16 * KC) {
            const int c  = tid >> 4;
            const int xs = (tid & 15) << 2;
            const float4 v = *reinterpret_cast<const float4*>(
                &in1[in_b_off + ((c0 + c) * 64 + y) * 64 + xs]);
            *reinterpret_cast<float4*>(&lds1[c][xs]) = v;
        }
        // ---- stage in2: KC*21 rows x 26 float4 slots (16 data + 10 zero-pad) ----
        for (int i = tid; i < KC * NROW * 26; i += 512) {
            const int row = i / 26;
            const int s   = i - row * 26;
            const int c   = row / NROW;
            const int rr  = row - c * NROW;
            const int yy  = y + 2 * rr - 20;
            float4 v = make_float4(0.f, 0.f, 0.f, 0.f);
            int col;
            if (s < 16) {                       // data slots: cols 20..83 <- x 0..63
                col = 20 + (s << 2);
                if (yy >= 0 && yy < 64) {
                    v = *reinterpret_cast<const float4*>(
                        &in2[in_b_off + ((c0 + c) * 64 + yy) * 64 + (s << 2)]);
                }
            } else if (s < 21) {                // left zero pad: cols 0..19
                col = (s - 16) << 2;
            } else {                            // right zero pad: cols 84..103
                col = 84 + ((s - 21) << 2);
            }
            *reinterpret_cast<float4*>(&lds2[c][rr][col]) = v;
        }
        __syncthreads();

        if (active) {
#pragma unroll
            for (int c = 0; c < KC; ++c) {
                float a[8], w[24];
                const float4* ap = reinterpret_cast<const float4*>(&lds1[c][xg << 3]);
                float4 a0 = ap[0], a1 = ap[1];
                a[0]=a0.x; a[1]=a0.y; a[2]=a0.z; a[3]=a0.w;
                a[4]=a1.x; a[5]=a1.y; a[6]=a1.z; a[7]=a1.w;
                const float4* wp = reinterpret_cast<const float4*>(&lds2[c][r][wbase]);
#pragma unroll
                for (int q = 0; q < 6; ++q) {
                    float4 wv = wp[q];
                    w[4*q+0]=wv.x; w[4*q+1]=wv.y; w[4*q+2]=wv.z; w[4*q+3]=wv.w;
                }
                // col(x,dx) = 8xg + lx + 16dxg + 2j = wbase + (lx + 2j), lx+2j in [0,21]
#pragma unroll
                for (int j = 0; j < 8; ++j)
#pragma unroll
                    for (int lx = 0; lx < 8; ++lx)
                        acc[j][lx] += a[lx] * w[lx + 2 * j];
            }
        }
        __syncthreads();
    }

    if (active) {
        const float scale = 1.f / 256.f;
#pragma unroll
        for (int j = 0; j < 8; ++j) {
            const int dxi = (dxg << 3) + j;
            if (dxi < 21) {
                const int d = r * 21 + dxi;
                const int base = ((b * 441 + d) * 64 + y) * 64 + (xg << 3);
                float4 v0 = make_float4(acc[j][0] * scale, acc[j][1] * scale,
                                        acc[j][2] * scale, acc[j][3] * scale);
                float4 v1 = make_float4(acc[j][4] * scale, acc[j][5] * scale,
                                        acc[j][6] * scale, acc[j][7] * scale);
                *reinterpret_cast<float4*>(&out[base])     = v0;
                *reinterpret_cast<float4*>(&out[base + 4]) = v1;
            }
        }
    }
}

extern "C" void kernel_launch(void* const* d_in, const int* in_sizes, int n_in,
                              void* d_out, int out_size, void* d_ws, size_t ws_size,
                              hipStream_t stream) {
    const float* in1 = (const float*)d_in[0];
    const float* in2 = (const float*)d_in[1];
    float* out = (float*)d_out;
    corr_kernel<<<dim3(512), dim3(512), 0, stream>>>(in1, in2, out);
}

// Round 2
// 153.879 us; speedup vs baseline: 2.1751x; 2.1751x over previous
//
#include <hip/hip_runtime.h>
#include <hip/hip_bf16.h>

// FlowNetC correlation via bf16 MFMA, fp32 accumulate.
// out[b, r*21+dx, y, x] = (1/256) * sum_c in1[b,c,y,x] * in2[b,c, y+2r-20, x+2dx-20]
//
// Per block (b, y): S[x, col] = sum_c A[c,x] * W[c,col]  (A = in1 row, W = padded in2 row,
// col = x + 2dx + 20 in [0,104)), then out[dx,x] = S[x, x+2dx] * (1/256).
// 8 waves: wave (m = w&3, nh = w>>2) computes S-tiles (Mtile m) x (Ntiles m+2nh, m+2nh+1),
// K = 256 reduced by 8 MFMAs (16x16x32 bf16) per tile. A-frags live in VGPRs for the
// whole block (in1 row reused across all 21 dy). Epilogue: diagonal gather through
// slds -> coalesced global stores.
//
// LDS B layout: [col][cd] packed bf16x2, col stride 134 dwords (== 6 mod 32):
// staging writes (lane = x) and ds_read_b64 frag reads (lane = col) are both <=2-way.

typedef short    bf16x8 __attribute__((ext_vector_type(8)));
typedef float    f32x4  __attribute__((ext_vector_type(4)));
typedef unsigned u32x2  __attribute__((ext_vector_type(2)));

constexpr int CSTRIDE = 64 * 64;        // channel plane
constexpr int BSTRIDE = 256 * CSTRIDE;  // batch
constexpr int NCOLS   = 112;            // padded cols (104 used + 8 guard for m=3 tiles)
constexpr int CSTR    = 134;            // dwords per col (128 data + 6 pad; 134 % 32 == 6)

union BF2 { __hip_bfloat162 h; unsigned u; };

__device__ inline unsigned pack_bf2(float lo, float hi) {
    BF2 cv;
    cv.h = __float22bfloat162_rn(make_float2(lo, hi));
    return cv.u;
}

__global__ __launch_bounds__(512, 4)
void corr_mfma(const float* __restrict__ in1,
               const float* __restrict__ in2,
               float* __restrict__ out)
{
    __shared__ __align__(16) unsigned blds[NCOLS * CSTR];  // 60,032 B
    __shared__ float slds[21 * 65];                        //  5,460 B

    const int tid  = threadIdx.x;
    const int lane = tid & 63;
    const int w    = tid >> 6;          // wave 0..7
    const int b    = blockIdx.x & 7;    // same-b blocks -> same XCD L2
    const int y    = blockIdx.x >> 3;

    const int cl = lane & 15;           // MFMA m/n lane index
    const int q  = lane >> 4;           // MFMA quad
    const int m  = w & 3;               // M-tile (x in [16m, 16m+16))
    const int nh = w >> 2;              // n-half

    const float* i1b = in1 + b * BSTRIDE;
    const float* i2b = in2 + b * BSTRIDE;

    // ---- A fragments: A[m_row = cl][k_local = 8q + j], k = 32k_idx + k_local ----
    bf16x8 afrag[8];
#pragma unroll
    for (int k = 0; k < 8; ++k) {
        const float* p = i1b + (32 * k + 8 * q) * CSTRIDE + y * 64 + 16 * m + cl;
        float v[8];
#pragma unroll
        for (int j = 0; j < 8; ++j) v[j] = p[j * CSTRIDE];
#pragma unroll
        for (int j = 0; j < 4; ++j)
            ((unsigned*)&afrag[k])[j] = pack_bf2(v[2 * j], v[2 * j + 1]);
    }

    // ---- zero-pad cols 0..19 and 84..111 (cd 0..127), once per block ----
    for (int i = tid; i < 48 * 128; i += 512) {
        const int colz = i >> 7;
        const int col  = (colz < 20) ? colz : colz + 64;
        blds[col * CSTR + (i & 127)] = 0u;
    }

    const int xs  = 16 * m + cl;   // staging x for this thread (16 consecutive per quad)
    const int cd0 = q + 4 * nh;    // staging cd base (cd = packed channel-pair index)

    for (int r = 0; r < 21; ++r) {
        const int yy = y + 2 * r - 20;
        const int ob = (b * 441 + r * 21) * CSTRIDE + y * 64;

        if (yy < 0 || yy > 63) {   // block-uniform: whole dy row is zero
            for (int i = tid; i < 21 * 64; i += 512)
                out[ob + (i >> 6) * CSTRIDE + (i & 63)] = 0.f;
            continue;
        }

        // ---- stage W_r: in2[b, :, yy, :] fp32 -> bf16x2 in LDS [col=x+20][cd] ----
        {
            const float* p   = i2b + yy * 64 + xs;
            unsigned*    dst = &blds[(xs + 20) * CSTR + cd0];
#pragma unroll
            for (int i = 0; i < 16; ++i) {
                const int c  = 2 * (cd0 + 8 * i);
                const float a0 = p[c * CSTRIDE];
                const float a1 = p[(c + 1) * CSTRIDE];
                dst[8 * i] = pack_bf2(a0, a1);
            }
        }
        __syncthreads();

        // ---- MFMA: S-tiles (m, n) for n = m+2nh, m+2nh+1 ----
#pragma unroll
        for (int nn = 0; nn < 2; ++nn) {
            const int n     = m + 2 * nh + nn;
            const int baddr = (16 * n + cl) * CSTR + 4 * q;   // + 16k, 8B aligned
            f32x4 acc = {0.f, 0.f, 0.f, 0.f};
#pragma unroll
            for (int k = 0; k < 8; ++k) {
                bf16x8 bfrag;
                ((u32x2*)&bfrag)[0] = *(const u32x2*)&blds[baddr + 16 * k];
                ((u32x2*)&bfrag)[1] = *(const u32x2*)&blds[baddr + 16 * k + 2];
                acc = __builtin_amdgcn_mfma_f32_16x16x32_bf16(afrag[k], bfrag, acc, 0, 0, 0);
            }
            // epilogue: D[row = 4q+i, col = cl]; gx = 16m+row, gcol = 16n+cl
            const int gcol = 16 * n + cl;
#pragma unroll
            for (int i = 0; i < 4; ++i) {
                const int gx = 16 * m + 4 * q + i;
                const int d2 = gcol - gx;                     // = 2*dx if valid
                if (d2 >= 0 && d2 <= 40 && !(d2 & 1))
                    slds[(d2 >> 1) * 65 + gx] = acc[i];
            }
        }
        __syncthreads();

        // ---- coalesced store of the 21x64 output rows for this r ----
        for (int i = tid; i < 21 * 64; i += 512) {
            const int dx = i >> 6, gx = i & 63;
            out[ob + dx * CSTRIDE + gx] = slds[dx * 65 + gx] * (1.f / 256.f);
        }
    }
}

extern "C" void kernel_launch(void* const* d_in, const int* in_sizes, int n_in,
                              void* d_out, int out_size, void* d_ws, size_t ws_size,
                              hipStream_t stream) {
    const float* in1 = (const float*)d_in[0];
    const float* in2 = (const float*)d_in[1];
    float* out = (float*)d_out;
    corr_mfma<<<dim3(512), dim3(512), 0, stream>>>(in1, in2, out);
}